// Round 1
// baseline (1126.467 us; speedup 1.0000x reference)
//
#include <hip/hip_runtime.h>
#include <hip/hip_bf16.h>
#include <stddef.h>

#define NROWS 8192
#define MAXD 128

// ---------------------------------------------------------------------------
// Kernel 1: scan dense A_pos once; build ELL neighbor lists, degree, deg^-1/2.
// deg[i] = (# nonzeros in row i of A_pos) + 1  (self loop from A_hat = A+I).
// A stray diagonal 1 in A_pos stays in the list (A_hat diag = 2 then) — exact.
// ---------------------------------------------------------------------------
__global__ __launch_bounds__(256) void build_adj(
    const float* __restrict__ A, int* __restrict__ ell,
    int* __restrict__ cnt, float* __restrict__ dinv)
{
    int row = blockIdx.x;
    const float4* arow = (const float4*)(A + (size_t)row * NROWS);
    __shared__ int scnt;
    if (threadIdx.x == 0) scnt = 0;
    __syncthreads();
    int* erow = ell + (size_t)row * MAXD;
    for (int q = threadIdx.x; q < NROWS / 4; q += 256) {
        float4 v = arow[q];
        int j = q * 4;
        if (v.x != 0.f) { int s = atomicAdd(&scnt, 1); if (s < MAXD) erow[s] = j; }
        if (v.y != 0.f) { int s = atomicAdd(&scnt, 1); if (s < MAXD) erow[s] = j + 1; }
        if (v.z != 0.f) { int s = atomicAdd(&scnt, 1); if (s < MAXD) erow[s] = j + 2; }
        if (v.w != 0.f) { int s = atomicAdd(&scnt, 1); if (s < MAXD) erow[s] = j + 3; }
    }
    __syncthreads();
    if (threadIdx.x == 0) {
        int c = scnt; if (c > MAXD) c = MAXD;
        cnt[row] = c;
        dinv[row] = rsqrtf((float)scnt + 1.0f);
    }
}

// ---------------------------------------------------------------------------
// Tiled f32 GEMM: C[M][N] = A[M][K] @ W[K][N] (+ bias).  Row-major all.
// Handles ragged K/N (62) via zero-filled LDS staging + scalar fallback when
// rows aren't 16B-aligned.
// ---------------------------------------------------------------------------
template<int BM, int BN, int BK, int TM, int TN>
__global__ __launch_bounds__((BM / TM) * (BN / TN)) void gemm_bias(
    const float* __restrict__ A, const float* __restrict__ W,
    const float* __restrict__ bias, float* __restrict__ C,
    int M, int N, int K)
{
    constexpr int NTH = (BM / TM) * (BN / TN);
    constexpr int TPC = BN / TN;
    __shared__ float As[BK][BM + 4]; // +4 keeps rows 16B-aligned, breaks bank conflicts
    __shared__ float Bs[BK][BN];
    int tid = threadIdx.x;
    int tn = tid % TPC, tm = tid / TPC;
    int bm0 = blockIdx.x * BM, bn0 = blockIdx.y * BN;
    float acc[TM][TN];
#pragma unroll
    for (int i = 0; i < TM; i++)
#pragma unroll
        for (int j = 0; j < TN; j++) acc[i][j] = 0.f;

    const bool a_vec = ((K & 3) == 0);        // K=1024/256 → float4 path; K=62 → scalar
    const bool b_vec = ((N & 3) == 0);        // N=256/64 → float4 path; N=62 → scalar

    for (int k0 = 0; k0 < K; k0 += BK) {
        if (a_vec) {
            for (int i = tid; i < BM * BK / 4; i += NTH) {
                int m = i / (BK / 4);
                int kq = (i % (BK / 4)) * 4;
                float4 v = {0.f, 0.f, 0.f, 0.f};
                int gm = bm0 + m, gk = k0 + kq;
                if (gm < M && gk < K) v = *(const float4*)(A + (size_t)gm * K + gk);
                As[kq + 0][m] = v.x; As[kq + 1][m] = v.y;
                As[kq + 2][m] = v.z; As[kq + 3][m] = v.w;
            }
        } else {
            for (int i = tid; i < BM * BK; i += NTH) {
                int m = i / BK, kk = i % BK;
                int gm = bm0 + m, gk = k0 + kk;
                float v = 0.f;
                if (gm < M && gk < K) v = A[(size_t)gm * K + gk];
                As[kk][m] = v;
            }
        }
        if (b_vec) {
            for (int i = tid; i < BK * BN / 4; i += NTH) {
                int kk = i / (BN / 4);
                int nq = (i % (BN / 4)) * 4;
                float4 v = {0.f, 0.f, 0.f, 0.f};
                int gk = k0 + kk, gn = bn0 + nq;
                if (gk < K && gn < N) v = *(const float4*)(W + (size_t)gk * N + gn);
                *(float4*)&Bs[kk][nq] = v;
            }
        } else {
            for (int i = tid; i < BK * BN; i += NTH) {
                int kk = i / BN, nn = i % BN;
                int gk = k0 + kk, gn = bn0 + nn;
                float v = 0.f;
                if (gk < K && gn < N) v = W[(size_t)gk * N + gn];
                Bs[kk][nn] = v;
            }
        }
        __syncthreads();
#pragma unroll
        for (int kk = 0; kk < BK; ++kk) {
            float a[TM], b[TN];
#pragma unroll
            for (int i = 0; i < TM; i++) a[i] = As[kk][tm * TM + i];
#pragma unroll
            for (int j = 0; j < TN; j++) b[j] = Bs[kk][tn * TN + j];
#pragma unroll
            for (int i = 0; i < TM; i++)
#pragma unroll
                for (int j = 0; j < TN; j++)
                    acc[i][j] = fmaf(a[i], b[j], acc[i][j]);
        }
        __syncthreads();
    }
#pragma unroll
    for (int i = 0; i < TM; i++) {
        int gm = bm0 + tm * TM + i;
        if (gm >= M) continue;
#pragma unroll
        for (int j = 0; j < TN; j++) {
            int gn = bn0 + tn * TN + j;
            if (gn < N) {
                float v = acc[i][j];
                if (bias) v += bias[gn];
                C[(size_t)gm * N + gn] = v;
            }
        }
    }
}

// ---------------------------------------------------------------------------
// Fused SpMM epilogue:  out = base + wscale * act( A_norm @ T + gb )
//   A_norm @ T row i  =  dinv_i * ( dinv_i*T[i] + sum_j dinv_j*T[j] )
// One block per row; thread = feature column (coalesced row reads of T).
// ---------------------------------------------------------------------------
__global__ void spmm_ep(const float* __restrict__ T,
                        const int* __restrict__ ell, const int* __restrict__ cnt,
                        const float* __restrict__ dinv,
                        const float* __restrict__ base,
                        const float* __restrict__ gb,
                        float* __restrict__ out,
                        int F, float wscale, int do_relu)
{
    int row = blockIdx.x;
    int f = threadIdx.x;
    if (f >= F) return;
    float di = dinv[row];
    const int* nb = ell + (size_t)row * MAXD;
    int c = cnt[row];
    float acc = di * T[(size_t)row * F + f];        // self-loop (identity) term
    for (int e = 0; e < c; ++e) {
        int j = nb[e];
        acc = fmaf(dinv[j], T[(size_t)j * F + f], acc);
    }
    float v = fmaf(di, acc, gb[f]);
    if (do_relu) v = fmaxf(v, 0.f);
    out[(size_t)row * F + f] = fmaf(wscale, v, base[(size_t)row * F + f]);
}

// ---------------------------------------------------------------------------
static inline void gemm_big(const float* A, const float* W, const float* bias,
                            float* C, int M, int N, int K, hipStream_t s)
{
    dim3 grid((M + 127) / 128, (N + 63) / 64);
    gemm_bias<128, 64, 16, 8, 4><<<grid, 256, 0, s>>>(A, W, bias, C, M, N, K);
}
static inline void gemm_small(const float* A, const float* W, const float* bias,
                              float* C, int M, int N, int K, hipStream_t s)
{
    dim3 grid((M + 63) / 64, (N + 63) / 64);
    gemm_bias<64, 64, 16, 4, 4><<<grid, 256, 0, s>>>(A, W, bias, C, M, N, K);
}

extern "C" void kernel_launch(void* const* d_in, const int* in_sizes, int n_in,
                              void* d_out, int out_size, void* d_ws, size_t ws_size,
                              hipStream_t stream)
{
    const float* x    = (const float*)d_in[0];
    const float* Apos = (const float*)d_in[1];
    const float* W1 = (const float*)d_in[2];  const float* b1  = (const float*)d_in[3];
    const float* W2 = (const float*)d_in[4];  const float* b2  = (const float*)d_in[5];
    const float* W3 = (const float*)d_in[6];  const float* b3  = (const float*)d_in[7];
    const float* G1 = (const float*)d_in[8];  const float* gb1 = (const float*)d_in[9];
    const float* G2 = (const float*)d_in[10]; const float* gb2 = (const float*)d_in[11];
    const float* G3 = (const float*)d_in[12]; const float* gb3 = (const float*)d_in[13];
    const float* G4 = (const float*)d_in[14]; const float* gb4 = (const float*)d_in[15];
    const float* G5 = (const float*)d_in[16]; const float* gb5 = (const float*)d_in[17];
    const float* G6 = (const float*)d_in[18]; const float* gb6 = (const float*)d_in[19];

    char* ws = (char*)d_ws;
    size_t off = 0;
    auto alloc = [&](size_t bytes) -> void* {
        void* p = ws + off;
        off = (off + bytes + 255) & ~(size_t)255;
        return p;
    };
    int*   ell  = (int*)  alloc((size_t)NROWS * MAXD * 4);
    int*   cnt  = (int*)  alloc((size_t)NROWS * 4);
    float* dinv = (float*)alloc((size_t)NROWS * 4);
    float* bufA = (float*)alloc((size_t)NROWS * 256 * 4);
    float* bufB = (float*)alloc((size_t)NROWS * 256 * 4);
    float* bufT = (float*)alloc((size_t)NROWS * 256 * 4);
    float* bufC = (float*)alloc((size_t)NROWS * 62 * 4);
    float* bufD = (float*)alloc((size_t)NROWS * 62 * 4);
    float* outp = (float*)d_out;

    // adjacency: one 256 MB pass
    build_adj<<<NROWS, 256, 0, stream>>>(Apos, ell, cnt, dinv);

    // L1: x1 = x1_lin + relu(An @ (x1_lin@G1) + gb1)
    gemm_big(x, W1, b1, bufA, NROWS, 256, 1024, stream);               // A = x1_lin
    gemm_big(bufA, G1, nullptr, bufT, NROWS, 256, 256, stream);
    spmm_ep<<<NROWS, 256, 0, stream>>>(bufT, ell, cnt, dinv, bufA, gb1, bufB, 256, 1.0f, 1); // B = x1
    // L2 (62-wide)
    gemm_small(bufB, W2, b2, bufC, NROWS, 62, 256, stream);            // C = x2_lin
    gemm_small(bufC, G2, nullptr, bufT, NROWS, 62, 62, stream);
    spmm_ep<<<NROWS, 64, 0, stream>>>(bufT, ell, cnt, dinv, bufC, gb2, bufD, 62, 1.0f, 1);   // D = x2
    // L3
    gemm_big(bufD, W3, b3, bufA, NROWS, 256, 62, stream);              // A = x3_lin
    gemm_big(bufA, G3, nullptr, bufT, NROWS, 256, 256, stream);
    spmm_ep<<<NROWS, 256, 0, stream>>>(bufT, ell, cnt, dinv, bufA, gb3, bufB, 256, 0.5f, 1); // B = x3
    // L4
    gemm_big(bufB, G4, nullptr, bufT, NROWS, 256, 256, stream);
    spmm_ep<<<NROWS, 256, 0, stream>>>(bufT, ell, cnt, dinv, bufB, gb4, bufA, 256, 0.5f, 1); // A = x4
    // L5
    gemm_big(bufA, G5, nullptr, bufT, NROWS, 256, 256, stream);
    spmm_ep<<<NROWS, 256, 0, stream>>>(bufT, ell, cnt, dinv, bufA, gb5, bufB, 256, 0.25f, 1); // B = x5
    // L6 (no relu)
    gemm_big(bufB, G6, nullptr, bufT, NROWS, 256, 256, stream);
    spmm_ep<<<NROWS, 256, 0, stream>>>(bufT, ell, cnt, dinv, bufB, gb6, outp, 256, 0.25f, 0); // out = x6
}

// Round 9
// 812.736 us; speedup vs baseline: 1.3860x; 1.3860x over previous
//
#include <hip/hip_runtime.h>
#include <hip/hip_bf16.h>
#include <stddef.h>
#include <stdint.h>

#define NROWS 8192
#define MAXD 128

typedef __attribute__((ext_vector_type(8))) short bf16x8;
typedef __attribute__((ext_vector_type(4))) float f32x4;
typedef __attribute__((ext_vector_type(4))) unsigned short u16x4;

static __device__ __forceinline__ unsigned short f2bf(float f) {
    unsigned int u = __float_as_uint(f);
    unsigned int r = (u + 0x7FFFu + ((u >> 16) & 1u)) >> 16;
    return (unsigned short)r;
}
static __device__ __forceinline__ float bf2f(unsigned short h) {
    return __uint_as_float(((unsigned int)h) << 16);
}

// ---------------------------------------------------------------------------
// ELL adjacency build: one 256 MB pass over dense A_pos.
// deg[i] = nnz(row i) + 1 (self loop). Diagonal entries of A_pos stay in the
// list, so A_hat diag = 2 there — exactly matches A_pos + I.
// ---------------------------------------------------------------------------
__global__ __launch_bounds__(256) void build_adj(
    const float* __restrict__ A, int* __restrict__ ell,
    int* __restrict__ cnt, float* __restrict__ dinv)
{
    int row = blockIdx.x;
    const float4* arow = (const float4*)(A + (size_t)row * NROWS);
    __shared__ int scnt;
    if (threadIdx.x == 0) scnt = 0;
    __syncthreads();
    int* erow = ell + (size_t)row * MAXD;
    for (int q = threadIdx.x; q < NROWS / 4; q += 256) {
        float4 v = arow[q];
        int j = q * 4;
        if (v.x != 0.f) { int s = atomicAdd(&scnt, 1); if (s < MAXD) erow[s] = j; }
        if (v.y != 0.f) { int s = atomicAdd(&scnt, 1); if (s < MAXD) erow[s] = j + 1; }
        if (v.z != 0.f) { int s = atomicAdd(&scnt, 1); if (s < MAXD) erow[s] = j + 2; }
        if (v.w != 0.f) { int s = atomicAdd(&scnt, 1); if (s < MAXD) erow[s] = j + 3; }
    }
    __syncthreads();
    if (threadIdx.x == 0) {
        int c = scnt; if (c > MAXD) c = MAXD;
        cnt[row] = c;
        dinv[row] = rsqrtf((float)scnt + 1.0f);
    }
}

// ---------------------------------------------------------------------------
// Weight transpose + hi/lo bf16 split with zero padding:
//   W[K][N] f32 (row-major)  ->  ht/lt [Npad][Kpad] bf16 (K-major rows).
// ---------------------------------------------------------------------------
__global__ __launch_bounds__(256) void tconv(
    const float* __restrict__ W, unsigned short* __restrict__ ht,
    unsigned short* __restrict__ lt, int K, int N, int Kpad, int Npad)
{
    int idx = blockIdx.x * 256 + threadIdx.x;
    if (idx >= Npad * Kpad) return;
    int n = idx / Kpad, k = idx % Kpad;
    float v = (k < K && n < N) ? W[(size_t)k * N + n] : 0.f;
    unsigned short hv = f2bf(v);
    ht[idx] = hv;
    lt[idx] = f2bf(v - bf2f(hv));
}

// Zero-pad a small f32 vector to 64 entries (biases for the 62-wide layers).
__global__ void pad64(const float* __restrict__ src, float* __restrict__ dst, int n)
{
    int i = threadIdx.x;
    dst[i] = (i < n) ? src[i] : 0.f;
}

// ---------------------------------------------------------------------------
// MFMA GEMM, split-bf16 (a=ah+al, b=bh+bl; 3 MFMA per logical product,
// dropping al*bl ~ 2^-16 relative), f32 accumulate.
//   A: f32 [M][K] row-major (K multiple of 64; row stride == K).
//   B: (Bth,Btl) bf16 [N][K] K-major (pre-transposed, pre-split weights).
//   C: f32 [M][N] (+bias).
// Tile 128x64, BK=64, 4 waves of 64x32. A's h/l split happens during LDS
// staging. XOR swizzle byte^((row&7)<<4) on BOTH LDS write and read (rule #21).
// LDS: As_h[16K] As_l[16K] Bs_h[8K] Bs_l[8K] = 48 KB, row stride 128 B.
// ---------------------------------------------------------------------------
__global__ __launch_bounds__(256) void gemm_mfma(
    const float* __restrict__ A,
    const unsigned short* __restrict__ Bth, const unsigned short* __restrict__ Btl,
    const float* __restrict__ bias,
    float* __restrict__ C, int K, int N)
{
    __shared__ __attribute__((aligned(16))) char smem[49152];
    const int tid = threadIdx.x;
    const int lane = tid & 63;
    const int w = tid >> 6;
    const int bm0 = blockIdx.x * 128;
    const int bn0 = blockIdx.y * 64;
    const int m_off = (w & 1) * 64;   // wave tile: 64 rows x 32 cols
    const int n_off = (w >> 1) * 32;

    f32x4 acc[4][2];
#pragma unroll
    for (int i = 0; i < 4; i++)
#pragma unroll
        for (int j = 0; j < 2; j++) acc[i][j] = (f32x4){0.f, 0.f, 0.f, 0.f};

    for (int k0 = 0; k0 < K; k0 += 64) {
        // ---- A tile: 128 rows x 64 k f32 = 2048 f32x4 quads; 8 per thread.
        // h/l split in-register; 8B stores share the 16B slot's XOR (bits>=4).
#pragma unroll
        for (int i = 0; i < 8; ++i) {
            int q = tid + i * 256;
            int row = q >> 4;               // 16 quads per 64-element row
            int kq = (q & 15) * 4;          // element offset within row
            f32x4 v = *(const f32x4*)(A + (size_t)(bm0 + row) * K + k0 + kq);
            u16x4 hv, lv;
#pragma unroll
            for (int j = 0; j < 4; ++j) {
                unsigned short hh = f2bf(v[j]);
                hv[j] = hh;
                lv[j] = f2bf(v[j] - bf2f(hh));
            }
            int logb = kq * 2;              // byte offset within 128B row
            int swz = (row << 7) + (logb ^ ((row & 7) << 4));
            *(u16x4*)(smem + swz) = hv;
            *(u16x4*)(smem + 16384 + swz) = lv;
        }
        // ---- B tiles: h and l, each 64 rows x 64 k bf16 = 512 x 16B chunks.
#pragma unroll
        for (int i = 0; i < 4; ++i) {
            int c = tid + i * 256;
            int half = c >> 9;              // 0 = h, 1 = l
            int cc = c & 511;
            int row = cc >> 3;              // 8 chunks per 128B row
            int logb = (cc & 7) * 16;
            const unsigned short* s =
                (half ? Btl : Bth) + (size_t)(bn0 + row) * K + k0 + (logb >> 1);
            bf16x8 v = *(const bf16x8*)s;
            int swz = (row << 7) + (logb ^ ((row & 7) << 4));
            *(bf16x8*)(smem + 32768 + (half << 13) + swz) = v;
        }
        __syncthreads();

#pragma unroll
        for (int kk = 0; kk < 64; kk += 32) {
            bf16x8 ah[4], al[4], bh[2], bl[2];
            int kb = (kk + ((lane >> 4) * 8)) * 2;   // byte offset of lane's k-octet
#pragma unroll
            for (int mi = 0; mi < 4; mi++) {
                int row = m_off + mi * 16 + (lane & 15);
                int off = (row << 7) + (kb ^ ((row & 7) << 4));
                ah[mi] = *(const bf16x8*)(smem + off);
                al[mi] = *(const bf16x8*)(smem + 16384 + off);
            }
#pragma unroll
            for (int ni = 0; ni < 2; ni++) {
                int row = n_off + ni * 16 + (lane & 15);
                int off = (row << 7) + (kb ^ ((row & 7) << 4));
                bh[ni] = *(const bf16x8*)(smem + 32768 + off);
                bl[ni] = *(const bf16x8*)(smem + 40960 + off);
            }
#pragma unroll
            for (int mi = 0; mi < 4; mi++)
#pragma unroll
                for (int ni = 0; ni < 2; ni++) {
                    acc[mi][ni] = __builtin_amdgcn_mfma_f32_16x16x32_bf16(ah[mi], bh[ni], acc[mi][ni], 0, 0, 0);
                    acc[mi][ni] = __builtin_amdgcn_mfma_f32_16x16x32_bf16(ah[mi], bl[ni], acc[mi][ni], 0, 0, 0);
                    acc[mi][ni] = __builtin_amdgcn_mfma_f32_16x16x32_bf16(al[mi], bh[ni], acc[mi][ni], 0, 0, 0);
                }
        }
        __syncthreads();
    }

    // ---- epilogue: C/D layout col=lane&15, row=(lane>>4)*4+reg  [m89/m91]
#pragma unroll
    for (int mi = 0; mi < 4; mi++)
#pragma unroll
        for (int ni = 0; ni < 2; ni++) {
            int col = bn0 + n_off + ni * 16 + (lane & 15);
            float bv = bias ? bias[col] : 0.f;
            int rbase = bm0 + m_off + mi * 16 + ((lane >> 4) * 4);
#pragma unroll
            for (int r = 0; r < 4; r++)
                C[(size_t)(rbase + r) * N + col] = acc[mi][ni][r] + bv;
        }
}

// ---------------------------------------------------------------------------
// SpMM epilogue, F=256:  out = base + wscale * act( A_norm-row @ T + gb )
//   A_norm@T row i = dinv_i * ( dinv_i*T_i + sum_j dinv_j*T_j )
// One block (1 wave) per row, float4 over features, LDS-staged edge list,
// 4-deep independent accumulators to hide gather latency.
// ---------------------------------------------------------------------------
__global__ __launch_bounds__(64) void spmm_vec4(
    const float* __restrict__ T, const int* __restrict__ ell,
    const int* __restrict__ cnt, const float* __restrict__ dinv,
    const float* __restrict__ base, const float* __restrict__ gb,
    float* __restrict__ out, float wscale, int do_relu)
{
    __shared__ int nb[MAXD];
    __shared__ float dv[MAXD];
    int row = blockIdx.x;
    int t = threadIdx.x;
    int c = cnt[row];
    for (int e = t; e < c; e += 64) {
        int j = ell[(size_t)row * MAXD + e];
        nb[e] = j;
        dv[e] = dinv[j];
    }
    __syncthreads();
    float di = dinv[row];
    f32x4 r = *(const f32x4*)(T + (size_t)row * 256 + t * 4) * di;
    f32x4 s1 = {0.f,0.f,0.f,0.f}, s2 = {0.f,0.f,0.f,0.f}, s3 = {0.f,0.f,0.f,0.f};
    int e = 0;
    for (; e + 4 <= c; e += 4) {
        r  += dv[e]     * *(const f32x4*)(T + (size_t)nb[e]     * 256 + t * 4);
        s1 += dv[e + 1] * *(const f32x4*)(T + (size_t)nb[e + 1] * 256 + t * 4);
        s2 += dv[e + 2] * *(const f32x4*)(T + (size_t)nb[e + 2] * 256 + t * 4);
        s3 += dv[e + 3] * *(const f32x4*)(T + (size_t)nb[e + 3] * 256 + t * 4);
    }
    for (; e < c; ++e)
        r += dv[e] * *(const f32x4*)(T + (size_t)nb[e] * 256 + t * 4);
    r = (r + s1) + (s2 + s3);
    f32x4 g = *(const f32x4*)(gb + t * 4);
    f32x4 b4 = *(const f32x4*)(base + (size_t)row * 256 + t * 4);
    f32x4 o4;
#pragma unroll
    for (int j = 0; j < 4; ++j) {
        float v = fmaf(di, r[j], g[j]);
        if (do_relu) v = fmaxf(v, 0.f);
        o4[j] = fmaf(wscale, v, b4[j]);
    }
    *(f32x4*)(out + (size_t)row * 256 + t * 4) = o4;
}

// F=64 scalar variant (padded 62-wide layer). T/base/gb pads are exactly 0,
// so uniform compute keeps output pads exactly 0 (relu(0)+0 = 0).
__global__ __launch_bounds__(64) void spmm64(
    const float* __restrict__ T, const int* __restrict__ ell,
    const int* __restrict__ cnt, const float* __restrict__ dinv,
    const float* __restrict__ base, const float* __restrict__ gb,
    float* __restrict__ out)
{
    __shared__ int nb[MAXD];
    __shared__ float dv[MAXD];
    int row = blockIdx.x;
    int f = threadIdx.x;
    int c = cnt[row];
    for (int e = f; e < c; e += 64) {
        int j = ell[(size_t)row * MAXD + e];
        nb[e] = j;
        dv[e] = dinv[j];
    }
    __syncthreads();
    float di = dinv[row];
    float r = di * T[(size_t)row * 64 + f];
    float p1 = 0.f, p2 = 0.f, p3 = 0.f;
    int e = 0;
    for (; e + 4 <= c; e += 4) {
        r  = fmaf(dv[e],     T[(size_t)nb[e]     * 64 + f], r);
        p1 = fmaf(dv[e + 1], T[(size_t)nb[e + 1] * 64 + f], p1);
        p2 = fmaf(dv[e + 2], T[(size_t)nb[e + 2] * 64 + f], p2);
        p3 = fmaf(dv[e + 3], T[(size_t)nb[e + 3] * 64 + f], p3);
    }
    for (; e < c; ++e) r = fmaf(dv[e], T[(size_t)nb[e] * 64 + f], r);
    r = (r + p1) + (p2 + p3);
    float v = fmaf(di, r, gb[f]);
    v = fmaxf(v, 0.f);
    out[(size_t)row * 64 + f] = v + base[(size_t)row * 64 + f];
}

// ---------------------------------------------------------------------------
static inline void mfma(const float* A, const unsigned short* Bth,
                        const unsigned short* Btl, const float* bias,
                        float* C, int K, int N, hipStream_t s)
{
    dim3 grid(NROWS / 128, N / 64);
    gemm_mfma<<<grid, 256, 0, s>>>(A, Bth, Btl, bias, C, K, N);
}

extern "C" void kernel_launch(void* const* d_in, const int* in_sizes, int n_in,
                              void* d_out, int out_size, void* d_ws, size_t ws_size,
                              hipStream_t stream)
{
    const float* x    = (const float*)d_in[0];
    const float* Apos = (const float*)d_in[1];
    const float* W1 = (const float*)d_in[2];  const float* b1  = (const float*)d_in[3];
    const float* W2 = (const float*)d_in[4];  const float* b2  = (const float*)d_in[5];
    const float* W3 = (const float*)d_in[6];  const float* b3  = (const float*)d_in[7];
    const float* G1 = (const float*)d_in[8];  const float* gb1 = (const float*)d_in[9];
    const float* G2 = (const float*)d_in[10]; const float* gb2 = (const float*)d_in[11];
    const float* G3 = (const float*)d_in[12]; const float* gb3 = (const float*)d_in[13];
    const float* G4 = (const float*)d_in[14]; const float* gb4 = (const float*)d_in[15];
    const float* G5 = (const float*)d_in[16]; const float* gb5 = (const float*)d_in[17];
    const float* G6 = (const float*)d_in[18]; const float* gb6 = (const float*)d_in[19];

    char* ws = (char*)d_ws;
    size_t off = 0;
    auto alloc = [&](size_t bytes) -> void* {
        void* p = ws + off;
        off = (off + bytes + 255) & ~(size_t)255;
        return p;
    };
    int*   ell  = (int*)  alloc((size_t)NROWS * MAXD * 4);
    int*   cnt  = (int*)  alloc((size_t)NROWS * 4);
    float* dinv = (float*)alloc((size_t)NROWS * 4);
    unsigned short* W1th = (unsigned short*)alloc(256 * 1024 * 2);
    unsigned short* W1tl = (unsigned short*)alloc(256 * 1024 * 2);
    unsigned short* W2th = (unsigned short*)alloc(64 * 256 * 2);
    unsigned short* W2tl = (unsigned short*)alloc(64 * 256 * 2);
    unsigned short* W3th = (unsigned short*)alloc(256 * 64 * 2);
    unsigned short* W3tl = (unsigned short*)alloc(256 * 64 * 2);
    unsigned short* G1th = (unsigned short*)alloc(256 * 256 * 2);
    unsigned short* G1tl = (unsigned short*)alloc(256 * 256 * 2);
    unsigned short* G2th = (unsigned short*)alloc(64 * 64 * 2);
    unsigned short* G2tl = (unsigned short*)alloc(64 * 64 * 2);
    unsigned short* G3th = (unsigned short*)alloc(256 * 256 * 2);
    unsigned short* G3tl = (unsigned short*)alloc(256 * 256 * 2);
    unsigned short* G4th = (unsigned short*)alloc(256 * 256 * 2);
    unsigned short* G4tl = (unsigned short*)alloc(256 * 256 * 2);
    unsigned short* G5th = (unsigned short*)alloc(256 * 256 * 2);
    unsigned short* G5tl = (unsigned short*)alloc(256 * 256 * 2);
    unsigned short* G6th = (unsigned short*)alloc(256 * 256 * 2);
    unsigned short* G6tl = (unsigned short*)alloc(256 * 256 * 2);
    float* b2p  = (float*)alloc(64 * 4);
    float* gb2p = (float*)alloc(64 * 4);
    float* lin  = (float*)alloc((size_t)NROWS * 256 * 4);   // x?_lin
    float* T    = (float*)alloc((size_t)NROWS * 256 * 4);   // GCN pre-aggregate
    float* hA   = (float*)alloc((size_t)NROWS * 256 * 4);   // activations ping
    float* hB   = (float*)alloc((size_t)NROWS * 256 * 4);   // activations pong
    // Padded 62-wide layer aliases dead large buffers (lifetimes desk-checked):
    float* x2lin = lin;   // written after x1_lin is dead
    float* T62   = T;     // written after L1's T is dead
    float* x2    = hB;    // written after spmm64 (reads lin/T), dead once x3_lin built
    float* outp = (float*)d_out;

    // adjacency: one 256 MB pass
    build_adj<<<NROWS, 256, 0, stream>>>(Apos, ell, cnt, dinv);

    // weight transpose + split (+pad to multiples of 64)
    tconv<<<(256 * 1024 + 255) / 256, 256, 0, stream>>>(W1, W1th, W1tl, 1024, 256, 1024, 256);
    tconv<<<(64 * 256 + 255) / 256, 256, 0, stream>>>(W2, W2th, W2tl, 256, 62, 256, 64);
    tconv<<<(256 * 64 + 255) / 256, 256, 0, stream>>>(W3, W3th, W3tl, 62, 256, 64, 256);
    tconv<<<(256 * 256 + 255) / 256, 256, 0, stream>>>(G1, G1th, G1tl, 256, 256, 256, 256);
    tconv<<<(64 * 64 + 255) / 256, 256, 0, stream>>>(G2, G2th, G2tl, 62, 62, 64, 64);
    tconv<<<(256 * 256 + 255) / 256, 256, 0, stream>>>(G3, G3th, G3tl, 256, 256, 256, 256);
    tconv<<<(256 * 256 + 255) / 256, 256, 0, stream>>>(G4, G4th, G4tl, 256, 256, 256, 256);
    tconv<<<(256 * 256 + 255) / 256, 256, 0, stream>>>(G5, G5th, G5tl, 256, 256, 256, 256);
    tconv<<<(256 * 256 + 255) / 256, 256, 0, stream>>>(G6, G6th, G6tl, 256, 256, 256, 256);
    pad64<<<1, 64, 0, stream>>>(b2, b2p, 62);
    pad64<<<1, 64, 0, stream>>>(gb2, gb2p, 62);

    // L1: x1_lin = x@W1+b1 ; x1 = x1_lin + relu(An@(x1_lin@G1)+gb1)
    mfma(x, W1th, W1tl, b1, lin, 1024, 256, stream);
    mfma(lin, G1th, G1tl, nullptr, T, 256, 256, stream);
    spmm_vec4<<<NROWS, 64, 0, stream>>>(T, ell, cnt, dinv, lin, gb1, hA, 1.0f, 1);   // hA = x1
    // L2 (62-wide, padded to 64); x1_lin/T now dead -> reuse as x2lin/T62
    mfma(hA, W2th, W2tl, b2p, x2lin, 256, 64, stream);
    mfma(x2lin, G2th, G2tl, nullptr, T62, 64, 64, stream);
    spmm64<<<NROWS, 64, 0, stream>>>(T62, ell, cnt, dinv, x2lin, gb2p, x2);          // x2=hB (pads 0)
    // L3
    mfma(x2, W3th, W3tl, b3, lin, 64, 256, stream);
    mfma(lin, G3th, G3tl, nullptr, T, 256, 256, stream);
    spmm_vec4<<<NROWS, 64, 0, stream>>>(T, ell, cnt, dinv, lin, gb3, hB, 0.5f, 1);   // hB = x3
    // L4
    mfma(hB, G4th, G4tl, nullptr, T, 256, 256, stream);
    spmm_vec4<<<NROWS, 64, 0, stream>>>(T, ell, cnt, dinv, hB, gb4, hA, 0.5f, 1);    // hA = x4
    // L5
    mfma(hA, G5th, G5tl, nullptr, T, 256, 256, stream);
    spmm_vec4<<<NROWS, 64, 0, stream>>>(T, ell, cnt, dinv, hA, gb5, hB, 0.25f, 1);   // hB = x5
    // L6 (no relu)
    mfma(hB, G6th, G6tl, nullptr, T, 256, 256, stream);
    spmm_vec4<<<NROWS, 64, 0, stream>>>(T, ell, cnt, dinv, hB, gb6, outp, 0.25f, 0); // out = x6
}

// Round 10
// 747.278 us; speedup vs baseline: 1.5074x; 1.0876x over previous
//
#include <hip/hip_runtime.h>
#include <hip/hip_bf16.h>
#include <stddef.h>
#include <stdint.h>

#define NROWS 8192
#define MAXD 128

typedef __attribute__((ext_vector_type(8))) short bf16x8;
typedef __attribute__((ext_vector_type(4))) float f32x4;
typedef __attribute__((ext_vector_type(4))) unsigned short u16x4;

static __device__ __forceinline__ unsigned short f2bf(float f) {
    unsigned int u = __float_as_uint(f);
    unsigned int r = (u + 0x7FFFu + ((u >> 16) & 1u)) >> 16;
    return (unsigned short)r;
}
static __device__ __forceinline__ float bf2f(unsigned short h) {
    return __uint_as_float(((unsigned int)h) << 16);
}
// unpack 4 bf16 features packed in uint2 (little-endian order)
static __device__ __forceinline__ f32x4 unpack4(uint2 u) {
    f32x4 f;
    f[0] = __uint_as_float(u.x << 16);
    f[1] = __uint_as_float(u.x & 0xFFFF0000u);
    f[2] = __uint_as_float(u.y << 16);
    f[3] = __uint_as_float(u.y & 0xFFFF0000u);
    return f;
}

// ---------------------------------------------------------------------------
// ELL adjacency build: one 256 MB pass over dense A_pos.
// deg[i] = nnz(row i) + 1 (self loop). Diagonal entries of A_pos stay in the
// list, so A_hat diag = 2 there — exactly matches A_pos + I.
// ---------------------------------------------------------------------------
__global__ __launch_bounds__(256) void build_adj(
    const float* __restrict__ A, int* __restrict__ ell,
    int* __restrict__ cnt, float* __restrict__ dinv)
{
    int row = blockIdx.x;
    const float4* arow = (const float4*)(A + (size_t)row * NROWS);
    __shared__ int scnt;
    if (threadIdx.x == 0) scnt = 0;
    __syncthreads();
    int* erow = ell + (size_t)row * MAXD;
    for (int q = threadIdx.x; q < NROWS / 4; q += 256) {
        float4 v = arow[q];
        int j = q * 4;
        if (v.x != 0.f) { int s = atomicAdd(&scnt, 1); if (s < MAXD) erow[s] = j; }
        if (v.y != 0.f) { int s = atomicAdd(&scnt, 1); if (s < MAXD) erow[s] = j + 1; }
        if (v.z != 0.f) { int s = atomicAdd(&scnt, 1); if (s < MAXD) erow[s] = j + 2; }
        if (v.w != 0.f) { int s = atomicAdd(&scnt, 1); if (s < MAXD) erow[s] = j + 3; }
    }
    __syncthreads();
    if (threadIdx.x == 0) {
        int c = scnt; if (c > MAXD) c = MAXD;
        cnt[row] = c;
        dinv[row] = rsqrtf((float)scnt + 1.0f);
    }
}

// ---------------------------------------------------------------------------
// Weight transpose + hi/lo bf16 split with zero padding:
//   W[K][N] f32 (row-major)  ->  ht/lt [Npad][Kpad] bf16 (K-major rows).
// ---------------------------------------------------------------------------
__global__ __launch_bounds__(256) void tconv(
    const float* __restrict__ W, unsigned short* __restrict__ ht,
    unsigned short* __restrict__ lt, int K, int N, int Kpad, int Npad)
{
    int idx = blockIdx.x * 256 + threadIdx.x;
    if (idx >= Npad * Kpad) return;
    int n = idx / Kpad, k = idx % Kpad;
    float v = (k < K && n < N) ? W[(size_t)k * N + n] : 0.f;
    unsigned short hv = f2bf(v);
    ht[idx] = hv;
    lt[idx] = f2bf(v - bf2f(hv));
}

// Fused transpose+split for the five 256x256 G matrices (one launch).
__global__ __launch_bounds__(256) void tconvG5(
    const float* __restrict__ g1, const float* __restrict__ g3,
    const float* __restrict__ g4, const float* __restrict__ g5,
    const float* __restrict__ g6,
    unsigned short* __restrict__ h1, unsigned short* __restrict__ l1,
    unsigned short* __restrict__ h3, unsigned short* __restrict__ l3,
    unsigned short* __restrict__ h4, unsigned short* __restrict__ l4,
    unsigned short* __restrict__ h5, unsigned short* __restrict__ l5,
    unsigned short* __restrict__ h6, unsigned short* __restrict__ l6)
{
    const float* s; unsigned short* h; unsigned short* l;
    switch (blockIdx.y) {                  // uniform branch
        case 0:  s = g1; h = h1; l = l1; break;
        case 1:  s = g3; h = h3; l = l3; break;
        case 2:  s = g4; h = h4; l = l4; break;
        case 3:  s = g5; h = h5; l = l5; break;
        default: s = g6; h = h6; l = l6; break;
    }
    int idx = blockIdx.x * 256 + threadIdx.x;   // < 65536
    int n = idx >> 8, k = idx & 255;
    float v = s[(size_t)k * 256 + n];
    unsigned short hv = f2bf(v);
    h[idx] = hv;
    l[idx] = f2bf(v - bf2f(hv));
}

// Zero-pad b2/gb2 to 64 entries in a single launch.
__global__ void pad2(const float* __restrict__ b2, const float* __restrict__ gb2,
                     float* __restrict__ b2p, float* __restrict__ gb2p)
{
    int i = threadIdx.x;   // 128 threads
    if (i < 64) b2p[i] = (i < 62) ? b2[i] : 0.f;
    else { int j = i - 64; gb2p[j] = (j < 62) ? gb2[j] : 0.f; }
}

// ---------------------------------------------------------------------------
// MFMA GEMM, split-bf16 (a=ah+al, b=bh+bl; 3 MFMA per logical product,
// dropping al*bl ~ 2^-16 relative), f32 accumulate.
//   A: f32 [M][K] row-major (K multiple of 64; row stride == K).
//   B: (Bth,Btl) bf16 [N][K] K-major (pre-transposed, pre-split weights).
//   Output: C f32 and/or Cb bf16 (either may be null).
// Tile 128x64, BK=64, 4 waves of 64x32. A's h/l split happens during LDS
// staging. XOR swizzle byte^((row&7)<<4) on BOTH LDS write and read (rule #21).
// LDS: As_h[16K] As_l[16K] Bs_h[8K] Bs_l[8K] = 48 KB, row stride 128 B.
// ---------------------------------------------------------------------------
__global__ __launch_bounds__(256) void gemm_mfma(
    const float* __restrict__ A,
    const unsigned short* __restrict__ Bth, const unsigned short* __restrict__ Btl,
    const float* __restrict__ bias,
    float* __restrict__ C, unsigned short* __restrict__ Cb, int K, int N)
{
    __shared__ __attribute__((aligned(16))) char smem[49152];
    const int tid = threadIdx.x;
    const int lane = tid & 63;
    const int w = tid >> 6;
    const int bm0 = blockIdx.x * 128;
    const int bn0 = blockIdx.y * 64;
    const int m_off = (w & 1) * 64;   // wave tile: 64 rows x 32 cols
    const int n_off = (w >> 1) * 32;

    f32x4 acc[4][2];
#pragma unroll
    for (int i = 0; i < 4; i++)
#pragma unroll
        for (int j = 0; j < 2; j++) acc[i][j] = (f32x4){0.f, 0.f, 0.f, 0.f};

    for (int k0 = 0; k0 < K; k0 += 64) {
        // ---- A tile: 128 rows x 64 k f32 = 2048 f32x4 quads; 8 per thread.
#pragma unroll
        for (int i = 0; i < 8; ++i) {
            int q = tid + i * 256;
            int row = q >> 4;               // 16 quads per 64-element row
            int kq = (q & 15) * 4;          // element offset within row
            f32x4 v = *(const f32x4*)(A + (size_t)(bm0 + row) * K + k0 + kq);
            u16x4 hv, lv;
#pragma unroll
            for (int j = 0; j < 4; ++j) {
                unsigned short hh = f2bf(v[j]);
                hv[j] = hh;
                lv[j] = f2bf(v[j] - bf2f(hh));
            }
            int logb = kq * 2;              // byte offset within 128B row
            int swz = (row << 7) + (logb ^ ((row & 7) << 4));
            *(u16x4*)(smem + swz) = hv;
            *(u16x4*)(smem + 16384 + swz) = lv;
        }
        // ---- B tiles: h and l, each 64 rows x 64 k bf16 = 512 x 16B chunks.
#pragma unroll
        for (int i = 0; i < 4; ++i) {
            int c = tid + i * 256;
            int half = c >> 9;              // 0 = h, 1 = l
            int cc = c & 511;
            int row = cc >> 3;              // 8 chunks per 128B row
            int logb = (cc & 7) * 16;
            const unsigned short* s =
                (half ? Btl : Bth) + (size_t)(bn0 + row) * K + k0 + (logb >> 1);
            bf16x8 v = *(const bf16x8*)s;
            int swz = (row << 7) + (logb ^ ((row & 7) << 4));
            *(bf16x8*)(smem + 32768 + (half << 13) + swz) = v;
        }
        __syncthreads();

#pragma unroll
        for (int kk = 0; kk < 64; kk += 32) {
            bf16x8 ah[4], al[4], bh[2], bl[2];
            int kb = (kk + ((lane >> 4) * 8)) * 2;   // byte offset of lane's k-octet
#pragma unroll
            for (int mi = 0; mi < 4; mi++) {
                int row = m_off + mi * 16 + (lane & 15);
                int off = (row << 7) + (kb ^ ((row & 7) << 4));
                ah[mi] = *(const bf16x8*)(smem + off);
                al[mi] = *(const bf16x8*)(smem + 16384 + off);
            }
#pragma unroll
            for (int ni = 0; ni < 2; ni++) {
                int row = n_off + ni * 16 + (lane & 15);
                int off = (row << 7) + (kb ^ ((row & 7) << 4));
                bh[ni] = *(const bf16x8*)(smem + 32768 + off);
                bl[ni] = *(const bf16x8*)(smem + 40960 + off);
            }
#pragma unroll
            for (int mi = 0; mi < 4; mi++)
#pragma unroll
                for (int ni = 0; ni < 2; ni++) {
                    acc[mi][ni] = __builtin_amdgcn_mfma_f32_16x16x32_bf16(ah[mi], bh[ni], acc[mi][ni], 0, 0, 0);
                    acc[mi][ni] = __builtin_amdgcn_mfma_f32_16x16x32_bf16(ah[mi], bl[ni], acc[mi][ni], 0, 0, 0);
                    acc[mi][ni] = __builtin_amdgcn_mfma_f32_16x16x32_bf16(al[mi], bh[ni], acc[mi][ni], 0, 0, 0);
                }
        }
        __syncthreads();
    }

    // ---- epilogue: C/D layout col=lane&15, row=(lane>>4)*4+reg  [m89/m91]
#pragma unroll
    for (int mi = 0; mi < 4; mi++)
#pragma unroll
        for (int ni = 0; ni < 2; ni++) {
            int col = bn0 + n_off + ni * 16 + (lane & 15);
            float bv = bias ? bias[col] : 0.f;
            int rbase = bm0 + m_off + mi * 16 + ((lane >> 4) * 4);
#pragma unroll
            for (int r = 0; r < 4; r++) {
                float v = acc[mi][ni][r] + bv;
                size_t idx = (size_t)(rbase + r) * N + col;
                if (C)  C[idx]  = v;
                if (Cb) Cb[idx] = f2bf(v);
            }
        }
}

// ---------------------------------------------------------------------------
// SpMM epilogue, F=256, bf16 T (4 MB -> per-XCD-L2-resident; half traffic):
//   out = base + wscale * act( A_norm-row @ T + gb )
//   A_norm@T row i = dinv_i * ( dinv_i*T_i + sum_j dinv_j*T_j )
// One block (1 wave) per row; lane t owns features 4t..4t+3 (uint2 load).
// ---------------------------------------------------------------------------
__global__ __launch_bounds__(64) void spmm_bf(
    const unsigned short* __restrict__ Tb, const int* __restrict__ ell,
    const int* __restrict__ cnt, const float* __restrict__ dinv,
    const float* __restrict__ base, const float* __restrict__ gb,
    float* __restrict__ out, float wscale, int do_relu)
{
    __shared__ int nb[MAXD];
    __shared__ float dv[MAXD];
    int row = blockIdx.x;
    int t = threadIdx.x;
    int c = cnt[row];
    for (int e = t; e < c; e += 64) {
        int j = ell[(size_t)row * MAXD + e];
        nb[e] = j;
        dv[e] = dinv[j];
    }
    __syncthreads();
    float di = dinv[row];
    f32x4 r = unpack4(*(const uint2*)(Tb + (size_t)row * 256 + t * 4)) * di;
    f32x4 s1 = {0.f,0.f,0.f,0.f}, s2 = {0.f,0.f,0.f,0.f}, s3 = {0.f,0.f,0.f,0.f};
    int e = 0;
    for (; e + 4 <= c; e += 4) {
        uint2 v0 = *(const uint2*)(Tb + (size_t)nb[e]     * 256 + t * 4);
        uint2 v1 = *(const uint2*)(Tb + (size_t)nb[e + 1] * 256 + t * 4);
        uint2 v2 = *(const uint2*)(Tb + (size_t)nb[e + 2] * 256 + t * 4);
        uint2 v3 = *(const uint2*)(Tb + (size_t)nb[e + 3] * 256 + t * 4);
        r  += dv[e]     * unpack4(v0);
        s1 += dv[e + 1] * unpack4(v1);
        s2 += dv[e + 2] * unpack4(v2);
        s3 += dv[e + 3] * unpack4(v3);
    }
    for (; e < c; ++e)
        r += dv[e] * unpack4(*(const uint2*)(Tb + (size_t)nb[e] * 256 + t * 4));
    r = (r + s1) + (s2 + s3);
    f32x4 g = *(const f32x4*)(gb + t * 4);
    f32x4 b4 = *(const f32x4*)(base + (size_t)row * 256 + t * 4);
    f32x4 o4;
#pragma unroll
    for (int j = 0; j < 4; ++j) {
        float v = fmaf(di, r[j], g[j]);
        if (do_relu) v = fmaxf(v, 0.f);
        o4[j] = fmaf(wscale, v, b4[j]);
    }
    *(f32x4*)(out + (size_t)row * 256 + t * 4) = o4;
}

// F=64 bf16-T variant (padded 62-wide layer). Pads stay exactly 0:
// zero weight rows -> T pads bf16(0)=0; relu(0)+base_pad(0)=0.
__global__ __launch_bounds__(64) void spmm64_bf(
    const unsigned short* __restrict__ Tb, const int* __restrict__ ell,
    const int* __restrict__ cnt, const float* __restrict__ dinv,
    const float* __restrict__ base, const float* __restrict__ gb,
    float* __restrict__ out)
{
    __shared__ int nb[MAXD];
    __shared__ float dv[MAXD];
    int row = blockIdx.x;
    int f = threadIdx.x;
    int c = cnt[row];
    for (int e = f; e < c; e += 64) {
        int j = ell[(size_t)row * MAXD + e];
        nb[e] = j;
        dv[e] = dinv[j];
    }
    __syncthreads();
    float di = dinv[row];
    float r = di * bf2f(Tb[(size_t)row * 64 + f]);
    float p1 = 0.f, p2 = 0.f, p3 = 0.f;
    int e = 0;
    for (; e + 4 <= c; e += 4) {
        r  = fmaf(dv[e],     bf2f(Tb[(size_t)nb[e]     * 64 + f]), r);
        p1 = fmaf(dv[e + 1], bf2f(Tb[(size_t)nb[e + 1] * 64 + f]), p1);
        p2 = fmaf(dv[e + 2], bf2f(Tb[(size_t)nb[e + 2] * 64 + f]), p2);
        p3 = fmaf(dv[e + 3], bf2f(Tb[(size_t)nb[e + 3] * 64 + f]), p3);
    }
    for (; e < c; ++e) r = fmaf(dv[e], bf2f(Tb[(size_t)nb[e] * 64 + f]), r);
    r = (r + p1) + (p2 + p3);
    float v = fmaf(di, r, gb[f]);
    v = fmaxf(v, 0.f);
    out[(size_t)row * 64 + f] = v + base[(size_t)row * 64 + f];
}

// ---------------------------------------------------------------------------
static inline void mfma(const float* A, const unsigned short* Bth,
                        const unsigned short* Btl, const float* bias,
                        float* C, unsigned short* Cb, int K, int N, hipStream_t s)
{
    dim3 grid(NROWS / 128, N / 64);
    gemm_mfma<<<grid, 256, 0, s>>>(A, Bth, Btl, bias, C, Cb, K, N);
}

extern "C" void kernel_launch(void* const* d_in, const int* in_sizes, int n_in,
                              void* d_out, int out_size, void* d_ws, size_t ws_size,
                              hipStream_t stream)
{
    const float* x    = (const float*)d_in[0];
    const float* Apos = (const float*)d_in[1];
    const float* W1 = (const float*)d_in[2];  const float* b1  = (const float*)d_in[3];
    const float* W2 = (const float*)d_in[4];  const float* b2  = (const float*)d_in[5];
    const float* W3 = (const float*)d_in[6];  const float* b3  = (const float*)d_in[7];
    const float* G1 = (const float*)d_in[8];  const float* gb1 = (const float*)d_in[9];
    const float* G2 = (const float*)d_in[10]; const float* gb2 = (const float*)d_in[11];
    const float* G3 = (const float*)d_in[12]; const float* gb3 = (const float*)d_in[13];
    const float* G4 = (const float*)d_in[14]; const float* gb4 = (const float*)d_in[15];
    const float* G5 = (const float*)d_in[16]; const float* gb5 = (const float*)d_in[17];
    const float* G6 = (const float*)d_in[18]; const float* gb6 = (const float*)d_in[19];

    char* ws = (char*)d_ws;
    size_t off = 0;
    auto alloc = [&](size_t bytes) -> void* {
        void* p = ws + off;
        off = (off + bytes + 255) & ~(size_t)255;
        return p;
    };
    int*   ell  = (int*)  alloc((size_t)NROWS * MAXD * 4);
    int*   cnt  = (int*)  alloc((size_t)NROWS * 4);
    float* dinv = (float*)alloc((size_t)NROWS * 4);
    unsigned short* W1th = (unsigned short*)alloc(256 * 1024 * 2);
    unsigned short* W1tl = (unsigned short*)alloc(256 * 1024 * 2);
    unsigned short* W2th = (unsigned short*)alloc(64 * 256 * 2);
    unsigned short* W2tl = (unsigned short*)alloc(64 * 256 * 2);
    unsigned short* W3th = (unsigned short*)alloc(256 * 64 * 2);
    unsigned short* W3tl = (unsigned short*)alloc(256 * 64 * 2);
    unsigned short* G1th = (unsigned short*)alloc(256 * 256 * 2);
    unsigned short* G1tl = (unsigned short*)alloc(256 * 256 * 2);
    unsigned short* G2th = (unsigned short*)alloc(64 * 64 * 2);
    unsigned short* G2tl = (unsigned short*)alloc(64 * 64 * 2);
    unsigned short* G3th = (unsigned short*)alloc(256 * 256 * 2);
    unsigned short* G3tl = (unsigned short*)alloc(256 * 256 * 2);
    unsigned short* G4th = (unsigned short*)alloc(256 * 256 * 2);
    unsigned short* G4tl = (unsigned short*)alloc(256 * 256 * 2);
    unsigned short* G5th = (unsigned short*)alloc(256 * 256 * 2);
    unsigned short* G5tl = (unsigned short*)alloc(256 * 256 * 2);
    unsigned short* G6th = (unsigned short*)alloc(256 * 256 * 2);
    unsigned short* G6tl = (unsigned short*)alloc(256 * 256 * 2);
    float* b2p  = (float*)alloc(64 * 4);
    float* gb2p = (float*)alloc(64 * 4);
    float* lin  = (float*)alloc((size_t)NROWS * 256 * 4);   // x?_lin (f32)
    unsigned short* Tb = (unsigned short*)alloc((size_t)NROWS * 256 * 2); // bf16 T
    float* hA   = (float*)alloc((size_t)NROWS * 256 * 4);   // activations ping
    float* hB   = (float*)alloc((size_t)NROWS * 256 * 4);   // activations pong
    // Padded 62-wide layer aliases dead larger buffers (lifetimes desk-checked):
    float* x2lin = lin;                    // written after x1_lin is dead
    unsigned short* T62b = Tb;             // written after L1's Tb is dead
    float* x2    = hB;                     // dead once x3_lin built
    float* outp = (float*)d_out;

    // adjacency: one 256 MB pass
    build_adj<<<NROWS, 256, 0, stream>>>(Apos, ell, cnt, dinv);

    // weight transpose + split (+pad to multiples of 64)
    tconv<<<(256 * 1024 + 255) / 256, 256, 0, stream>>>(W1, W1th, W1tl, 1024, 256, 1024, 256);
    tconv<<<(64 * 256 + 255) / 256, 256, 0, stream>>>(W2, W2th, W2tl, 256, 62, 256, 64);
    tconv<<<(256 * 64 + 255) / 256, 256, 0, stream>>>(W3, W3th, W3tl, 62, 256, 64, 256);
    tconv<<<(64 * 64 + 255) / 256, 256, 0, stream>>>(G2, G2th, G2tl, 62, 62, 64, 64);
    dim3 g5(256, 5);
    tconvG5<<<g5, 256, 0, stream>>>(G1, G3, G4, G5, G6,
                                    G1th, G1tl, G3th, G3tl, G4th, G4tl,
                                    G5th, G5tl, G6th, G6tl);
    pad2<<<1, 128, 0, stream>>>(b2, gb2, b2p, gb2p);

    // L1: x1_lin = x@W1+b1 ; x1 = x1_lin + relu(An@(x1_lin@G1)+gb1)
    mfma(x, W1th, W1tl, b1, lin, nullptr, 1024, 256, stream);
    mfma(lin, G1th, G1tl, nullptr, nullptr, Tb, 256, 256, stream);
    spmm_bf<<<NROWS, 64, 0, stream>>>(Tb, ell, cnt, dinv, lin, gb1, hA, 1.0f, 1);   // hA = x1
    // L2 (62-wide, padded to 64); x1_lin/Tb now dead -> reuse as x2lin/T62b
    mfma(hA, W2th, W2tl, b2p, x2lin, nullptr, 256, 64, stream);
    mfma(x2lin, G2th, G2tl, nullptr, nullptr, T62b, 64, 64, stream);
    spmm64_bf<<<NROWS, 64, 0, stream>>>(T62b, ell, cnt, dinv, x2lin, gb2p, x2);     // x2=hB (pads 0)
    // L3
    mfma(x2, W3th, W3tl, b3, lin, nullptr, 64, 256, stream);
    mfma(lin, G3th, G3tl, nullptr, nullptr, Tb, 256, 256, stream);
    spmm_bf<<<NROWS, 64, 0, stream>>>(Tb, ell, cnt, dinv, lin, gb3, hB, 0.5f, 1);   // hB = x3
    // L4
    mfma(hB, G4th, G4tl, nullptr, nullptr, Tb, 256, 256, stream);
    spmm_bf<<<NROWS, 64, 0, stream>>>(Tb, ell, cnt, dinv, hB, gb4, hA, 0.5f, 1);    // hA = x4
    // L5
    mfma(hA, G5th, G5tl, nullptr, nullptr, Tb, 256, 256, stream);
    spmm_bf<<<NROWS, 64, 0, stream>>>(Tb, ell, cnt, dinv, hA, gb5, hB, 0.25f, 1);   // hB = x5
    // L6 (no relu)
    mfma(hB, G6th, G6tl, nullptr, nullptr, Tb, 256, 256, stream);
    spmm_bf<<<NROWS, 64, 0, stream>>>(Tb, ell, cnt, dinv, hB, gb6, outp, 0.25f, 0); // out = x6
}

// Round 11
// 706.443 us; speedup vs baseline: 1.5946x; 1.0578x over previous
//
#include <hip/hip_runtime.h>
#include <hip/hip_bf16.h>
#include <stddef.h>
#include <stdint.h>

#define NROWS 8192
#define MAXD 128

typedef __attribute__((ext_vector_type(8))) short bf16x8;
typedef __attribute__((ext_vector_type(4))) float f32x4;
typedef __attribute__((ext_vector_type(4))) unsigned short u16x4;

static __device__ __forceinline__ unsigned short f2bf(float f) {
    unsigned int u = __float_as_uint(f);
    unsigned int r = (u + 0x7FFFu + ((u >> 16) & 1u)) >> 16;
    return (unsigned short)r;
}
static __device__ __forceinline__ float bf2f(unsigned short h) {
    return __uint_as_float(((unsigned int)h) << 16);
}
static __device__ __forceinline__ f32x4 unpack4(uint2 u) {
    f32x4 f;
    f[0] = __uint_as_float(u.x << 16);
    f[1] = __uint_as_float(u.x & 0xFFFF0000u);
    f[2] = __uint_as_float(u.y << 16);
    f[3] = __uint_as_float(u.y & 0xFFFF0000u);
    return f;
}

// ---------------------------------------------------------------------------
// Mega-prep: ONE dispatch does adjacency + all weight transpose/split + the
// fused products W@G (so layers 1-3 need a single GEMM each).
// Block ranges (grid = 11653):
//   [0,8192)        build_adj row b
//   [8192,9216)     W1^T      -> B1 rows [0,256)   (k=b', n=tid, K=1024)
//   [9216,10240)    (W1@G1)^T -> B1 rows [256,512)
//   [10240,10496)   W2^T      -> B2 rows [0,64)    (k=b', n=tid<64, K=256)
//   [10496,10752)   (W2@G2)^T -> B2 rows [64,128)
//   [10752,10816)   W3^T      -> B3 rows [0,256)   (k=b'<64, n=tid, K=64)
//   [10816,10880)   (W3@G3)^T -> B3 rows [256,512)
//   [10880,11648)   G4/G5/G6^T
//   [11648,11653)   bias vectors: bc1=[b1|b1@G1], bc2=[b2p|b2@G2]+gb2p,
//                   bc3=[b3|b3@G3]
// ---------------------------------------------------------------------------
__global__ __launch_bounds__(256) void prep_all(
    const float* __restrict__ A,
    int* __restrict__ ell, int* __restrict__ cnt, float* __restrict__ dinv,
    const float* __restrict__ W1, const float* __restrict__ W2,
    const float* __restrict__ W3,
    const float* __restrict__ G1, const float* __restrict__ G2,
    const float* __restrict__ G3, const float* __restrict__ G4,
    const float* __restrict__ G5, const float* __restrict__ G6,
    const float* __restrict__ b1, const float* __restrict__ b2,
    const float* __restrict__ b3, const float* __restrict__ gb2,
    unsigned short* __restrict__ B1h, unsigned short* __restrict__ B1l,
    unsigned short* __restrict__ B2h, unsigned short* __restrict__ B2l,
    unsigned short* __restrict__ B3h, unsigned short* __restrict__ B3l,
    unsigned short* __restrict__ G4h, unsigned short* __restrict__ G4l,
    unsigned short* __restrict__ G5h, unsigned short* __restrict__ G5l,
    unsigned short* __restrict__ G6h, unsigned short* __restrict__ G6l,
    float* __restrict__ bc1, float* __restrict__ bc2,
    float* __restrict__ bc3, float* __restrict__ gb2p)
{
    __shared__ int scnt;
    int b = blockIdx.x;
    int tid = threadIdx.x;

    if (b < 8192) {                       // ---- adjacency row b
        int row = b;
        const float4* arow = (const float4*)(A + (size_t)row * NROWS);
        if (tid == 0) scnt = 0;
        __syncthreads();
        int* erow = ell + (size_t)row * MAXD;
        for (int q = tid; q < NROWS / 4; q += 256) {
            float4 v = arow[q];
            int j = q * 4;
            if (v.x != 0.f) { int s = atomicAdd(&scnt, 1); if (s < MAXD) erow[s] = j; }
            if (v.y != 0.f) { int s = atomicAdd(&scnt, 1); if (s < MAXD) erow[s] = j + 1; }
            if (v.z != 0.f) { int s = atomicAdd(&scnt, 1); if (s < MAXD) erow[s] = j + 2; }
            if (v.w != 0.f) { int s = atomicAdd(&scnt, 1); if (s < MAXD) erow[s] = j + 3; }
        }
        __syncthreads();
        if (tid == 0) {
            int c = scnt; if (c > MAXD) c = MAXD;
            cnt[row] = c;
            dinv[row] = rsqrtf((float)scnt + 1.0f);
        }
        return;
    }
    b -= 8192;
    if (b < 1024) {                       // ---- W1^T  (K=1024)
        int k = b, n = tid;
        float v = W1[(size_t)k * 256 + n];
        unsigned short h = f2bf(v);
        B1h[(size_t)n * 1024 + k] = h;
        B1l[(size_t)n * 1024 + k] = f2bf(v - bf2f(h));
        return;
    }
    b -= 1024;
    if (b < 1024) {                       // ---- (W1@G1)^T
        int k = b, n = tid;
        float s = 0.f;
        for (int j = 0; j < 256; ++j)
            s = fmaf(W1[(size_t)k * 256 + j], G1[(size_t)j * 256 + n], s);
        unsigned short h = f2bf(s);
        B1h[(size_t)(256 + n) * 1024 + k] = h;
        B1l[(size_t)(256 + n) * 1024 + k] = f2bf(s - bf2f(h));
        return;
    }
    b -= 1024;
    if (b < 256) {                        // ---- W2^T (62->64 pad, K=256)
        if (tid < 64) {
            int k = b, n = tid;
            float v = (n < 62) ? W2[(size_t)k * 62 + n] : 0.f;
            unsigned short h = f2bf(v);
            B2h[(size_t)n * 256 + k] = h;
            B2l[(size_t)n * 256 + k] = f2bf(v - bf2f(h));
        }
        return;
    }
    b -= 256;
    if (b < 256) {                        // ---- (W2@G2)^T
        if (tid < 64) {
            int k = b, n = tid;
            float s = 0.f;
            if (n < 62)
                for (int j = 0; j < 62; ++j)
                    s = fmaf(W2[(size_t)k * 62 + j], G2[(size_t)j * 62 + n], s);
            unsigned short h = f2bf(s);
            B2h[(size_t)(64 + n) * 256 + k] = h;
            B2l[(size_t)(64 + n) * 256 + k] = f2bf(s - bf2f(h));
        }
        return;
    }
    b -= 256;
    if (b < 64) {                         // ---- W3^T (K=64 pad)
        int k = b, n = tid;
        float v = (k < 62) ? W3[(size_t)k * 256 + n] : 0.f;
        unsigned short h = f2bf(v);
        B3h[(size_t)n * 64 + k] = h;
        B3l[(size_t)n * 64 + k] = f2bf(v - bf2f(h));
        return;
    }
    b -= 64;
    if (b < 64) {                         // ---- (W3@G3)^T
        int k = b, n = tid;
        float s = 0.f;
        if (k < 62)
            for (int j = 0; j < 256; ++j)
                s = fmaf(W3[(size_t)k * 256 + j], G3[(size_t)j * 256 + n], s);
        unsigned short h = f2bf(s);
        B3h[(size_t)(256 + n) * 64 + k] = h;
        B3l[(size_t)(256 + n) * 64 + k] = f2bf(s - bf2f(h));
        return;
    }
    b -= 64;
    if (b < 768) {                        // ---- G4/G5/G6^T
        int g = b >> 8, k = b & 255, n = tid;
        const float* src = (g == 0) ? G4 : (g == 1) ? G5 : G6;
        unsigned short* hh = (g == 0) ? G4h : (g == 1) ? G5h : G6h;
        unsigned short* ll = (g == 0) ? G4l : (g == 1) ? G5l : G6l;
        float v = src[(size_t)k * 256 + n];
        unsigned short h = f2bf(v);
        hh[(size_t)n * 256 + k] = h;
        ll[(size_t)n * 256 + k] = f2bf(v - bf2f(h));
        return;
    }
    b -= 768;
    if (b == 0) {                         // bc1[0,256) = b1
        bc1[tid] = b1[tid];
    } else if (b == 1) {                  // bc1[256,512) = b1@G1
        float s = 0.f;
        for (int j = 0; j < 256; ++j) s = fmaf(b1[j], G1[(size_t)j * 256 + tid], s);
        bc1[256 + tid] = s;
    } else if (b == 2) {                  // bc2 = [b2 pad | b2@G2], gb2p
        if (tid < 64) {
            bc2[tid] = (tid < 62) ? b2[tid] : 0.f;
        } else if (tid < 128) {
            int n = tid - 64;
            float s = 0.f;
            if (n < 62)
                for (int j = 0; j < 62; ++j) s = fmaf(b2[j], G2[(size_t)j * 62 + n], s);
            bc2[64 + n] = s;
        } else if (tid < 192) {
            int n = tid - 128;
            gb2p[n] = (n < 62) ? gb2[n] : 0.f;
        }
    } else if (b == 3) {                  // bc3[0,256) = b3
        bc3[tid] = b3[tid];
    } else if (b == 4) {                  // bc3[256,512) = b3@G3
        float s = 0.f;
        for (int j = 0; j < 256; ++j) s = fmaf(b3[j], G3[(size_t)j * 256 + tid], s);
        bc3[256 + tid] = s;
    }
}

// ---------------------------------------------------------------------------
// MFMA GEMM, split-bf16, dual output:
//   A: f32 [M][K] row-major. B: (Bth,Btl) bf16 [N][K] K-major.
//   cols < nsplit  -> C  f32,  row stride nsplit      (x_lin part)
//   cols >= nsplit -> Cb bf16, row stride (N-nsplit)  (T part)
// Tile 128x64, BK=64, 4 waves of 64x32; XOR swizzle both sides (rule #21).
// ---------------------------------------------------------------------------
__global__ __launch_bounds__(256) void gemm_mfma(
    const float* __restrict__ A,
    const unsigned short* __restrict__ Bth, const unsigned short* __restrict__ Btl,
    const float* __restrict__ bias,
    float* __restrict__ C, unsigned short* __restrict__ Cb,
    int K, int N, int nsplit)
{
    __shared__ __attribute__((aligned(16))) char smem[49152];
    const int tid = threadIdx.x;
    const int lane = tid & 63;
    const int w = tid >> 6;
    const int bm0 = blockIdx.x * 128;
    const int bn0 = blockIdx.y * 64;
    const int m_off = (w & 1) * 64;
    const int n_off = (w >> 1) * 32;

    f32x4 acc[4][2];
#pragma unroll
    for (int i = 0; i < 4; i++)
#pragma unroll
        for (int j = 0; j < 2; j++) acc[i][j] = (f32x4){0.f, 0.f, 0.f, 0.f};

    for (int k0 = 0; k0 < K; k0 += 64) {
#pragma unroll
        for (int i = 0; i < 8; ++i) {     // A tile: split f32 -> h/l bf16
            int q = tid + i * 256;
            int row = q >> 4;
            int kq = (q & 15) * 4;
            f32x4 v = *(const f32x4*)(A + (size_t)(bm0 + row) * K + k0 + kq);
            u16x4 hv, lv;
#pragma unroll
            for (int j = 0; j < 4; ++j) {
                unsigned short hh = f2bf(v[j]);
                hv[j] = hh;
                lv[j] = f2bf(v[j] - bf2f(hh));
            }
            int logb = kq * 2;
            int swz = (row << 7) + (logb ^ ((row & 7) << 4));
            *(u16x4*)(smem + swz) = hv;
            *(u16x4*)(smem + 16384 + swz) = lv;
        }
#pragma unroll
        for (int i = 0; i < 4; ++i) {     // B tiles (h, l)
            int c = tid + i * 256;
            int half = c >> 9;
            int cc = c & 511;
            int row = cc >> 3;
            int logb = (cc & 7) * 16;
            const unsigned short* s =
                (half ? Btl : Bth) + (size_t)(bn0 + row) * K + k0 + (logb >> 1);
            bf16x8 v = *(const bf16x8*)s;
            int swz = (row << 7) + (logb ^ ((row & 7) << 4));
            *(bf16x8*)(smem + 32768 + (half << 13) + swz) = v;
        }
        __syncthreads();

#pragma unroll
        for (int kk = 0; kk < 64; kk += 32) {
            bf16x8 ah[4], al[4], bh[2], bl[2];
            int kb = (kk + ((lane >> 4) * 8)) * 2;
#pragma unroll
            for (int mi = 0; mi < 4; mi++) {
                int row = m_off + mi * 16 + (lane & 15);
                int off = (row << 7) + (kb ^ ((row & 7) << 4));
                ah[mi] = *(const bf16x8*)(smem + off);
                al[mi] = *(const bf16x8*)(smem + 16384 + off);
            }
#pragma unroll
            for (int ni = 0; ni < 2; ni++) {
                int row = n_off + ni * 16 + (lane & 15);
                int off = (row << 7) + (kb ^ ((row & 7) << 4));
                bh[ni] = *(const bf16x8*)(smem + 32768 + off);
                bl[ni] = *(const bf16x8*)(smem + 40960 + off);
            }
#pragma unroll
            for (int mi = 0; mi < 4; mi++)
#pragma unroll
                for (int ni = 0; ni < 2; ni++) {
                    acc[mi][ni] = __builtin_amdgcn_mfma_f32_16x16x32_bf16(ah[mi], bh[ni], acc[mi][ni], 0, 0, 0);
                    acc[mi][ni] = __builtin_amdgcn_mfma_f32_16x16x32_bf16(ah[mi], bl[ni], acc[mi][ni], 0, 0, 0);
                    acc[mi][ni] = __builtin_amdgcn_mfma_f32_16x16x32_bf16(al[mi], bh[ni], acc[mi][ni], 0, 0, 0);
                }
        }
        __syncthreads();
    }

    // epilogue: C/D layout col=lane&15, row=(lane>>4)*4+reg  [m89/m91]
    const int wb = N - nsplit;
#pragma unroll
    for (int mi = 0; mi < 4; mi++)
#pragma unroll
        for (int ni = 0; ni < 2; ni++) {
            int col = bn0 + n_off + ni * 16 + (lane & 15);
            float bv = bias ? bias[col] : 0.f;
            int rbase = bm0 + m_off + mi * 16 + ((lane >> 4) * 4);
#pragma unroll
            for (int r = 0; r < 4; r++) {
                float v = acc[mi][ni][r] + bv;
                if (col < nsplit)
                    C[(size_t)(rbase + r) * nsplit + col] = v;
                else
                    Cb[(size_t)(rbase + r) * wb + (col - nsplit)] = f2bf(v);
            }
        }
}

// ---------------------------------------------------------------------------
// SpMM epilogue, F=256, bf16 T:
//   out = base + wscale * act( dinv_i*(dinv_i*T_i + sum_j dinv_j*T_j) + gb )
// ---------------------------------------------------------------------------
__global__ __launch_bounds__(64) void spmm_bf(
    const unsigned short* __restrict__ Tb, const int* __restrict__ ell,
    const int* __restrict__ cnt, const float* __restrict__ dinv,
    const float* __restrict__ base, const float* __restrict__ gb,
    float* __restrict__ out, float wscale, int do_relu)
{
    __shared__ int nb[MAXD];
    __shared__ float dv[MAXD];
    int row = blockIdx.x;
    int t = threadIdx.x;
    int c = cnt[row];
    for (int e = t; e < c; e += 64) {
        int j = ell[(size_t)row * MAXD + e];
        nb[e] = j;
        dv[e] = dinv[j];
    }
    __syncthreads();
    float di = dinv[row];
    f32x4 r = unpack4(*(const uint2*)(Tb + (size_t)row * 256 + t * 4)) * di;
    f32x4 s1 = {0.f,0.f,0.f,0.f}, s2 = {0.f,0.f,0.f,0.f}, s3 = {0.f,0.f,0.f,0.f};
    int e = 0;
    for (; e + 4 <= c; e += 4) {
        uint2 v0 = *(const uint2*)(Tb + (size_t)nb[e]     * 256 + t * 4);
        uint2 v1 = *(const uint2*)(Tb + (size_t)nb[e + 1] * 256 + t * 4);
        uint2 v2 = *(const uint2*)(Tb + (size_t)nb[e + 2] * 256 + t * 4);
        uint2 v3 = *(const uint2*)(Tb + (size_t)nb[e + 3] * 256 + t * 4);
        r  += dv[e]     * unpack4(v0);
        s1 += dv[e + 1] * unpack4(v1);
        s2 += dv[e + 2] * unpack4(v2);
        s3 += dv[e + 3] * unpack4(v3);
    }
    for (; e < c; ++e)
        r += dv[e] * unpack4(*(const uint2*)(Tb + (size_t)nb[e] * 256 + t * 4));
    r = (r + s1) + (s2 + s3);
    f32x4 g = *(const f32x4*)(gb + t * 4);
    f32x4 b4 = *(const f32x4*)(base + (size_t)row * 256 + t * 4);
    f32x4 o4;
#pragma unroll
    for (int j = 0; j < 4; ++j) {
        float v = fmaf(di, r[j], g[j]);
        if (do_relu) v = fmaxf(v, 0.f);
        o4[j] = fmaf(wscale, v, b4[j]);
    }
    *(f32x4*)(out + (size_t)row * 256 + t * 4) = o4;
}

// F=64 variant (padded 62-wide layer); pads stay exactly 0.
__global__ __launch_bounds__(64) void spmm64_bf(
    const unsigned short* __restrict__ Tb, const int* __restrict__ ell,
    const int* __restrict__ cnt, const float* __restrict__ dinv,
    const float* __restrict__ base, const float* __restrict__ gb,
    float* __restrict__ out)
{
    __shared__ int nb[MAXD];
    __shared__ float dv[MAXD];
    int row = blockIdx.x;
    int f = threadIdx.x;
    int c = cnt[row];
    for (int e = f; e < c; e += 64) {
        int j = ell[(size_t)row * MAXD + e];
        nb[e] = j;
        dv[e] = dinv[j];
    }
    __syncthreads();
    float di = dinv[row];
    float r = di * bf2f(Tb[(size_t)row * 64 + f]);
    float p1 = 0.f, p2 = 0.f, p3 = 0.f;
    int e = 0;
    for (; e + 4 <= c; e += 4) {
        r  = fmaf(dv[e],     bf2f(Tb[(size_t)nb[e]     * 64 + f]), r);
        p1 = fmaf(dv[e + 1], bf2f(Tb[(size_t)nb[e + 1] * 64 + f]), p1);
        p2 = fmaf(dv[e + 2], bf2f(Tb[(size_t)nb[e + 2] * 64 + f]), p2);
        p3 = fmaf(dv[e + 3], bf2f(Tb[(size_t)nb[e + 3] * 64 + f]), p3);
    }
    for (; e < c; ++e) r = fmaf(dv[e], bf2f(Tb[(size_t)nb[e] * 64 + f]), r);
    r = (r + p1) + (p2 + p3);
    float v = fmaf(di, r, gb[f]);
    v = fmaxf(v, 0.f);
    out[(size_t)row * 64 + f] = v + base[(size_t)row * 64 + f];
}

// ---------------------------------------------------------------------------
static inline void mfma(const float* A, const unsigned short* Bth,
                        const unsigned short* Btl, const float* bias,
                        float* C, unsigned short* Cb, int K, int N, int nsplit,
                        hipStream_t s)
{
    dim3 grid(NROWS / 128, N / 64);
    gemm_mfma<<<grid, 256, 0, s>>>(A, Bth, Btl, bias, C, Cb, K, N, nsplit);
}

extern "C" void kernel_launch(void* const* d_in, const int* in_sizes, int n_in,
                              void* d_out, int out_size, void* d_ws, size_t ws_size,
                              hipStream_t stream)
{
    const float* x    = (const float*)d_in[0];
    const float* Apos = (const float*)d_in[1];
    const float* W1 = (const float*)d_in[2];  const float* b1  = (const float*)d_in[3];
    const float* W2 = (const float*)d_in[4];  const float* b2  = (const float*)d_in[5];
    const float* W3 = (const float*)d_in[6];  const float* b3  = (const float*)d_in[7];
    const float* G1 = (const float*)d_in[8];  const float* gb1 = (const float*)d_in[9];
    const float* G2 = (const float*)d_in[10]; const float* gb2 = (const float*)d_in[11];
    const float* G3 = (const float*)d_in[12]; const float* gb3 = (const float*)d_in[13];
    const float* G4 = (const float*)d_in[14]; const float* gb4 = (const float*)d_in[15];
    const float* G5 = (const float*)d_in[16]; const float* gb5 = (const float*)d_in[17];
    const float* G6 = (const float*)d_in[18]; const float* gb6 = (const float*)d_in[19];

    char* ws = (char*)d_ws;
    size_t off = 0;
    auto alloc = [&](size_t bytes) -> void* {
        void* p = ws + off;
        off = (off + bytes + 255) & ~(size_t)255;
        return p;
    };
    int*   ell  = (int*)  alloc((size_t)NROWS * MAXD * 4);
    int*   cnt  = (int*)  alloc((size_t)NROWS * 4);
    float* dinv = (float*)alloc((size_t)NROWS * 4);
    unsigned short* B1h = (unsigned short*)alloc(512 * 1024 * 2);
    unsigned short* B1l = (unsigned short*)alloc(512 * 1024 * 2);
    unsigned short* B2h = (unsigned short*)alloc(128 * 256 * 2);
    unsigned short* B2l = (unsigned short*)alloc(128 * 256 * 2);
    unsigned short* B3h = (unsigned short*)alloc(512 * 64 * 2);
    unsigned short* B3l = (unsigned short*)alloc(512 * 64 * 2);
    unsigned short* G4h = (unsigned short*)alloc(256 * 256 * 2);
    unsigned short* G4l = (unsigned short*)alloc(256 * 256 * 2);
    unsigned short* G5h = (unsigned short*)alloc(256 * 256 * 2);
    unsigned short* G5l = (unsigned short*)alloc(256 * 256 * 2);
    unsigned short* G6h = (unsigned short*)alloc(256 * 256 * 2);
    unsigned short* G6l = (unsigned short*)alloc(256 * 256 * 2);
    float* bc1  = (float*)alloc(512 * 4);
    float* bc2  = (float*)alloc(128 * 4);
    float* bc3  = (float*)alloc(512 * 4);
    float* gb2p = (float*)alloc(64 * 4);
    float* lin  = (float*)alloc((size_t)NROWS * 256 * 4);   // x?_lin (f32)
    unsigned short* Tb = (unsigned short*)alloc((size_t)NROWS * 256 * 2); // bf16 T
    float* hA   = (float*)alloc((size_t)NROWS * 256 * 4);
    float* hB   = (float*)alloc((size_t)NROWS * 256 * 4);
    // 62-wide layer aliases (lifetimes: producer completes before aliased write)
    float* x2lin = lin;                 // [8192][64] f32, written after L1 spmm
    unsigned short* T62b = Tb;          // [8192][64] bf16, after L1 spmm
    float* x2    = hB;                  // [8192][64] f32, dead once L3 GEMM done
    float* outp = (float*)d_out;

    // 1) prep: adjacency + all weight transforms + fused W@G products
    prep_all<<<11653, 256, 0, stream>>>(
        Apos, ell, cnt, dinv, W1, W2, W3, G1, G2, G3, G4, G5, G6,
        b1, b2, b3, gb2,
        B1h, B1l, B2h, B2l, B3h, B3l, G4h, G4l, G5h, G5l, G6h, G6l,
        bc1, bc2, bc3, gb2p);

    // 2) L1 dual: lin = x@W1+b1 (f32) ; Tb = x@(W1G1)+b1G1 (bf16)
    mfma(x, B1h, B1l, bc1, lin, Tb, 1024, 512, 256, stream);
    // 3) x1 = lin + relu(agg(Tb) + gb1)
    spmm_bf<<<NROWS, 64, 0, stream>>>(Tb, ell, cnt, dinv, lin, gb1, hA, 1.0f, 1);   // hA = x1
    // 4) L2 dual (62->64 pad): x2lin f32 | T62b bf16
    mfma(hA, B2h, B2l, bc2, x2lin, T62b, 256, 128, 64, stream);
    // 5) x2 = x2lin + relu(agg(T62b) + gb2)
    spmm64_bf<<<NROWS, 64, 0, stream>>>(T62b, ell, cnt, dinv, x2lin, gb2p, x2);     // x2 = hB[:,:64]
    // 6) L3 dual: lin = x2@W3+b3 | Tb = x2@(W3G3)+b3G3
    mfma(x2, B3h, B3l, bc3, lin, Tb, 64, 512, 256, stream);
    // 7) x3 = lin + 0.5*relu(agg + gb3)
    spmm_bf<<<NROWS, 64, 0, stream>>>(Tb, ell, cnt, dinv, lin, gb3, hB, 0.5f, 1);   // hB = x3
    // 8-9) L4
    mfma(hB, G4h, G4l, nullptr, nullptr, Tb, 256, 256, 0, stream);
    spmm_bf<<<NROWS, 64, 0, stream>>>(Tb, ell, cnt, dinv, hB, gb4, hA, 0.5f, 1);    // hA = x4
    // 10-11) L5
    mfma(hA, G5h, G5l, nullptr, nullptr, Tb, 256, 256, 0, stream);
    spmm_bf<<<NROWS, 64, 0, stream>>>(Tb, ell, cnt, dinv, hA, gb5, hB, 0.25f, 1);   // hB = x5
    // 12-13) L6 (no relu)
    mfma(hB, G6h, G6l, nullptr, nullptr, Tb, 256, 256, 0, stream);
    spmm_bf<<<NROWS, 64, 0, stream>>>(Tb, ell, cnt, dinv, hB, gb6, outp, 0.25f, 0); // out
}